// Round 2
// baseline (380.196 us; speedup 1.0000x reference)
//
#include <hip/hip_runtime.h>
#include <stdint.h>

#define N_PTS 262144
#define CDIM 128
#define BDIM 8
#define HID 256
#define TW 128
#define MAXB 2056
#define SCALE_F 0.17677669529663687f
#define LN_EPS 1e-5f

typedef unsigned short u16;
typedef __attribute__((ext_vector_type(8))) short short8v;
typedef __attribute__((ext_vector_type(4))) float f32x4;
typedef __attribute__((ext_vector_type(8))) float f32x8;

__device__ __forceinline__ u16 f2bf(float f){
  union { float f; uint32_t u; } v; v.f = f;
  uint32_t r = v.u + 0x7fffu + ((v.u>>16)&1u);
  return (u16)(r>>16);
}
__device__ __forceinline__ float bf2f(u16 u){
  union { uint32_t u; float f; } v; v.u = ((uint32_t)u)<<16; return v.f;
}

// ---------------- bucket id + histogram ----------------
__global__ __launch_bounds__(256) void k_bucket(const int* __restrict__ batch,
                                                const int* __restrict__ lengths,
                                                const float* __restrict__ scores,
                                                int* __restrict__ gb, int* __restrict__ hist){
  int i = blockIdx.x*256 + threadIdx.x;
  if(i >= N_PTS) return;
  int b = batch[i];
  int boff = 0, nb = 1;
  #pragma unroll
  for(int j=0;j<BDIM;j++){
    int nbj = (lengths[j] + TW - 1)/TW;
    if(j <  b) boff += nbj;
    if(j == b) nb = nbj;
  }
  float sc = scores[i];
  int local = (int)(sc * (float)nb);
  if(local > nb-1) local = nb-1;
  if(local < 0) local = 0;
  int g = local + boff;
  gb[i] = g;
  atomicAdd(&hist[g], 1);
}

// ---------------- exclusive scan over MAXB histogram ----------------
__global__ __launch_bounds__(256) void k_scan(const int* __restrict__ hist,
                                              int* __restrict__ start, int* __restrict__ cursor){
  __shared__ int ssum[256];
  const int t = threadIdx.x;
  const int CH = 9;              // 256*9 = 2304 >= 2056
  int loc[CH];
  int s = 0;
  #pragma unroll
  for(int i=0;i<CH;i++){
    int idx = t*CH + i;
    int v = (idx < MAXB) ? hist[idx] : 0;
    loc[i] = s; s += v;
  }
  ssum[t] = s; __syncthreads();
  for(int off=1; off<256; off<<=1){
    int v = (t>=off)? ssum[t-off] : 0;
    __syncthreads();
    ssum[t] += v;
    __syncthreads();
  }
  int ex = ssum[t] - s;          // exclusive prefix of this chunk
  #pragma unroll
  for(int i=0;i<CH;i++){
    int idx = t*CH + i;
    if(idx < MAXB){ int st = ex + loc[i]; start[idx] = st; cursor[idx] = st; }
  }
}

// ---------------- counting-sort scatter ----------------
__global__ __launch_bounds__(256) void k_scatter(const int* __restrict__ gb,
                                                 int* __restrict__ cursor, int* __restrict__ sidx){
  int i = blockIdx.x*256 + threadIdx.x;
  if(i >= N_PTS) return;
  int pos = atomicAdd(&cursor[gb[i]], 1);
  sidx[pos] = i;
}

// ---------------- per-bucket centroid of LN1(feat) ----------------
__global__ __launch_bounds__(256) void k_centroid(const float* __restrict__ feat,
                                                  const int* __restrict__ sidx,
                                                  const int* __restrict__ start,
                                                  const int* __restrict__ hist,
                                                  const float* __restrict__ g1, const float* __restrict__ b1,
                                                  float* __restrict__ cent){
  const int b = blockIdx.x;
  const int cnt = hist[b], st = start[b];
  const int tid = threadIdx.x;
  const int w = tid>>6, lane = tid&63;
  const int c0 = lane*2;
  float g1a = g1[c0], g1b = g1[c0+1];
  float b1a = b1[c0], b1b = b1[c0+1];
  float a0 = 0.f, a1 = 0.f;
  for(int i=w; i<cnt; i+=4){
    int p = sidx[st+i];
    const float* fp = feat + (size_t)p*CDIM + c0;
    float x0 = fp[0];
    float x1 = fp[1];
    float s = x0+x1, sq = x0*x0 + x1*x1;
    #pragma unroll
    for(int m=1;m<64;m<<=1){ s += __shfl_xor(s,m,64); sq += __shfl_xor(sq,m,64); }
    float mu = s*(1.f/128.f);
    float var = sq*(1.f/128.f) - mu*mu;
    float rs = rsqrtf(var + LN_EPS);
    a0 += (x0-mu)*rs*g1a + b1a;
    a1 += (x1-mu)*rs*g1b + b1b;
  }
  __shared__ float red[4][128];
  red[w][c0] = a0; red[w][c0+1] = a1;
  __syncthreads();
  if(tid < 128){
    float t = red[0][tid] + red[1][tid] + red[2][tid] + red[3][tid];
    float cf = (float)(cnt > 0 ? cnt : 1);
    cent[(size_t)b*CDIM + tid] = t / cf;
  }
}

// ---------------- centroid projections kc = cent@Wk+bk, vc = cent@Wv+bv ----------------
__global__ __launch_bounds__(128) void k_cgemm(const float* __restrict__ cent,
                                               const float* __restrict__ Wk, const float* __restrict__ bk,
                                               const float* __restrict__ Wv, const float* __restrict__ bv,
                                               float* __restrict__ kc, float* __restrict__ vc){
  const int b = blockIdx.x, t = threadIdx.x;
  __shared__ float sc[128];
  sc[t] = cent[(size_t)b*CDIM + t];
  __syncthreads();
  float ak = bk[t], av = bv[t];
  for(int d=0; d<CDIM; ++d){
    float c = sc[d];
    ak += c * Wk[d*CDIM + t];
    av += c * Wv[d*CDIM + t];
  }
  kc[(size_t)b*CDIM + t] = ak;
  vc[(size_t)b*CDIM + t] = av;
}

// ---------------- pack fp32 weight into bf16 per-MFMA-B-fragment layout ----------------
// dst[((kT*nCT + cT)*64 + lane)*8 + e] = bf16(W[(kT*32 + (lane>>4)*8 + e)*NC + cT*16 + (lane&15)])
__global__ __launch_bounds__(256) void k_pack(const float* __restrict__ W, u16* __restrict__ dst,
                                              int K, int NC){
  int idx = blockIdx.x*256 + threadIdx.x;
  if(idx >= K*NC) return;
  int e = idx & 7;
  int l = (idx>>3) & 63;
  int f = idx >> 9;
  int nCT = NC >> 4;
  int cT = f % nCT, kT = f / nCT;
  int k = kT*32 + (l>>4)*8 + e;
  int c = cT*16 + (l&15);
  dst[idx] = f2bf(W[k*NC + c]);
}

// ---------------- fused attention: LN1 -> Q -> gate -> Wp -> x1 = feat + x_out ----------------
__global__ __launch_bounds__(256) void k_attn(const float* __restrict__ feat,
                                              const int* __restrict__ gb,
                                              const float* __restrict__ kc, const float* __restrict__ vc,
                                              const u16* __restrict__ pWq, const u16* __restrict__ pWg,
                                              const u16* __restrict__ pWp,
                                              const float* __restrict__ bq, const float* __restrict__ bg,
                                              const float* __restrict__ bp,
                                              const float* __restrict__ g1, const float* __restrict__ b1,
                                              float* __restrict__ xout){
  __shared__ __align__(16) u16 bufA[64*128];   // x_ln (bf16), later gate
  __shared__ __align__(16) u16 bufQ[64*128];   // q (bf16)
  char* A8 = (char*)bufA;
  char* Q8 = (char*)bufQ;
  const int tid = threadIdx.x;
  const int wid = tid>>6, lane = tid&63;
  const int row0 = blockIdx.x*64;

  // ---- Phase A: stage LN1(feat) into bufA (swizzled bf16) ----
  {
    const int cb = (lane&15)*16;      // column byte
    const f32x8 gv  = *(const f32x8*)(g1 + (lane&15)*8);
    const f32x8 bv8 = *(const f32x8*)(b1 + (lane&15)*8);
    #pragma unroll
    for(int it=0; it<4; ++it){
      int rl = wid*16 + it*4 + (lane>>4);
      const f32x8 f8 = *(const f32x8*)(feat + (size_t)(row0+rl)*CDIM + (lane&15)*8);
      float s=0.f, sq=0.f;
      #pragma unroll
      for(int e=0;e<8;e++){ s += f8[e]; sq += f8[e]*f8[e]; }
      #pragma unroll
      for(int m=1;m<16;m<<=1){ s += __shfl_xor(s,m,64); sq += __shfl_xor(sq,m,64); }
      float mu = s*(1.f/128.f);
      float var = sq*(1.f/128.f) - mu*mu;
      float rs = rsqrtf(var + LN_EPS);
      short8v h;
      #pragma unroll
      for(int e=0;e<8;e++){
        float x = (f8[e]-mu)*rs*gv[e] + bv8[e];
        h[e] = (short)f2bf(x);
      }
      *(short8v*)(A8 + rl*256 + (cb ^ ((rl&7)<<4))) = h;
    }
  }
  __syncthreads();

  const int arow = wid*16 + (lane&15);
  const int kgrp = (lane>>4);

  // ---- Phase B: q = x_ln @ Wq + bq ----
  short8v af[4];
  #pragma unroll
  for(int kT=0;kT<4;kT++)
    af[kT] = *(const short8v*)(A8 + arow*256 + (((kT*64) + kgrp*16) ^ ((arow&7)<<4)));
  f32x4 acc[8];
  #pragma unroll
  for(int cT=0;cT<8;cT++){
    f32x4 a = {0.f,0.f,0.f,0.f};
    #pragma unroll
    for(int kT=0;kT<4;kT++){
      const short8v b8 = *(const short8v*)(pWq + ((size_t)((kT*8+cT)*64 + lane)*8));
      a = __builtin_amdgcn_mfma_f32_16x16x32_bf16(af[kT], b8, a, 0,0,0);
    }
    acc[cT] = a;
  }
  #pragma unroll
  for(int cT=0;cT<8;cT++){
    int col = cT*16 + (lane&15);
    float bqv = bq[col];
    #pragma unroll
    for(int r=0;r<4;r++){
      int rl = wid*16 + kgrp*4 + r;
      *(u16*)(Q8 + rl*256 + ((col*2) ^ ((rl&7)<<4))) = f2bf(acc[cT][r] + bqv);
    }
  }
  __syncthreads();

  const int myb = gb[row0 + arow];

  // ---- Phase C: gate = sigmoid((q*kc*SCALE) @ Wg + bg) -> bufA ----
  #pragma unroll
  for(int kT=0;kT<4;kT++){
    const short8v q8 = *(const short8v*)(Q8 + arow*256 + (((kT*64) + kgrp*16) ^ ((arow&7)<<4)));
    const f32x4 ka = *(const f32x4*)(kc + (size_t)myb*CDIM + kT*32 + kgrp*8);
    const f32x4 kb = *(const f32x4*)(kc + (size_t)myb*CDIM + kT*32 + kgrp*8 + 4);
    short8v a;
    #pragma unroll
    for(int e=0;e<4;e++) a[e]   = (short)f2bf(bf2f((u16)q8[e])   * ka[e] * SCALE_F);
    #pragma unroll
    for(int e=0;e<4;e++) a[e+4] = (short)f2bf(bf2f((u16)q8[e+4]) * kb[e] * SCALE_F);
    af[kT] = a;
  }
  #pragma unroll
  for(int cT=0;cT<8;cT++){
    f32x4 a = {0.f,0.f,0.f,0.f};
    #pragma unroll
    for(int kT=0;kT<4;kT++){
      const short8v b8 = *(const short8v*)(pWg + ((size_t)((kT*8+cT)*64 + lane)*8));
      a = __builtin_amdgcn_mfma_f32_16x16x32_bf16(af[kT], b8, a, 0,0,0);
    }
    acc[cT] = a;
  }
  #pragma unroll
  for(int cT=0;cT<8;cT++){
    int col = cT*16 + (lane&15);
    float bgv = bg[col];
    #pragma unroll
    for(int r=0;r<4;r++){
      int rl = wid*16 + kgrp*4 + r;
      float x = acc[cT][r] + bgv;
      float sg = 1.f/(1.f + __expf(-x));
      *(u16*)(A8 + rl*256 + ((col*2) ^ ((rl&7)<<4))) = f2bf(sg);
    }
  }
  __syncthreads();

  // ---- Phase D: x_out = (gate*vc) @ Wp + bp ; x1 = feat + x_out ----
  #pragma unroll
  for(int kT=0;kT<4;kT++){
    const short8v q8 = *(const short8v*)(A8 + arow*256 + (((kT*64) + kgrp*16) ^ ((arow&7)<<4)));
    const f32x4 va = *(const f32x4*)(vc + (size_t)myb*CDIM + kT*32 + kgrp*8);
    const f32x4 vb = *(const f32x4*)(vc + (size_t)myb*CDIM + kT*32 + kgrp*8 + 4);
    short8v a;
    #pragma unroll
    for(int e=0;e<4;e++) a[e]   = (short)f2bf(bf2f((u16)q8[e])   * va[e]);
    #pragma unroll
    for(int e=0;e<4;e++) a[e+4] = (short)f2bf(bf2f((u16)q8[e+4]) * vb[e]);
    af[kT] = a;
  }
  #pragma unroll
  for(int cT=0;cT<8;cT++){
    f32x4 a = {0.f,0.f,0.f,0.f};
    #pragma unroll
    for(int kT=0;kT<4;kT++){
      const short8v b8 = *(const short8v*)(pWp + ((size_t)((kT*8+cT)*64 + lane)*8));
      a = __builtin_amdgcn_mfma_f32_16x16x32_bf16(af[kT], b8, a, 0,0,0);
    }
    acc[cT] = a;
  }
  #pragma unroll
  for(int cT=0;cT<8;cT++){
    int col = cT*16 + (lane&15);
    float bpv = bp[col];
    #pragma unroll
    for(int r=0;r<4;r++){
      int rl = wid*16 + kgrp*4 + r;
      size_t gi = (size_t)(row0+rl)*CDIM + col;
      xout[gi] = feat[gi] + acc[cT][r] + bpv;
    }
  }
}

// ---------------- fused FFN: LN2 -> Wf1 -> LN+ReLU -> Wf2 -> out = x1 + ... ----------------
__global__ __launch_bounds__(256) void k_ffn(float* __restrict__ xio,
                                             const u16* __restrict__ pW1, const u16* __restrict__ pW2,
                                             const float* __restrict__ bias1, const float* __restrict__ gam_f,
                                             const float* __restrict__ bet_f, const float* __restrict__ bias2,
                                             const float* __restrict__ g2, const float* __restrict__ b2){
  __shared__ __align__(16) u16 bufH[64*128];   // LN2(x1) bf16
  __shared__ __align__(16) u16 bufT[64*256];   // relu(LN(h@Wf1+bf1)) bf16
  char* H8 = (char*)bufH;
  char* T8 = (char*)bufT;
  const int tid = threadIdx.x;
  const int wid = tid>>6, lane = tid&63;
  const int row0 = blockIdx.x*64;

  // ---- stage LN2(x1) ----
  {
    const int cb = (lane&15)*16;
    const f32x8 gv  = *(const f32x8*)(g2 + (lane&15)*8);
    const f32x8 bv8 = *(const f32x8*)(b2 + (lane&15)*8);
    #pragma unroll
    for(int it=0; it<4; ++it){
      int rl = wid*16 + it*4 + (lane>>4);
      const f32x8 f8 = *(const f32x8*)(xio + (size_t)(row0+rl)*CDIM + (lane&15)*8);
      float s=0.f, sq=0.f;
      #pragma unroll
      for(int e=0;e<8;e++){ s += f8[e]; sq += f8[e]*f8[e]; }
      #pragma unroll
      for(int m=1;m<16;m<<=1){ s += __shfl_xor(s,m,64); sq += __shfl_xor(sq,m,64); }
      float mu = s*(1.f/128.f);
      float var = sq*(1.f/128.f) - mu*mu;
      float rs = rsqrtf(var + LN_EPS);
      short8v h;
      #pragma unroll
      for(int e=0;e<8;e++){
        float x = (f8[e]-mu)*rs*gv[e] + bv8[e];
        h[e] = (short)f2bf(x);
      }
      *(short8v*)(H8 + rl*256 + (cb ^ ((rl&7)<<4))) = h;
    }
  }
  __syncthreads();

  const int arow = wid*16 + (lane&15);
  const int kgrp = (lane>>4);

  // ---- h @ Wf1 (128 -> 256) ----
  short8v af[8];
  #pragma unroll
  for(int kT=0;kT<4;kT++)
    af[kT] = *(const short8v*)(H8 + arow*256 + (((kT*64) + kgrp*16) ^ ((arow&7)<<4)));
  f32x4 acc[16];
  #pragma unroll
  for(int cT=0;cT<16;cT++){
    f32x4 a = {0.f,0.f,0.f,0.f};
    #pragma unroll
    for(int kT=0;kT<4;kT++){
      const short8v b8 = *(const short8v*)(pW1 + ((size_t)((kT*16+cT)*64 + lane)*8));
      a = __builtin_amdgcn_mfma_f32_16x16x32_bf16(af[kT], b8, a, 0,0,0);
    }
    acc[cT] = a;
  }
  // ---- inner LN over 256 + ReLU -> bufT ----
  #pragma unroll
  for(int r=0;r<4;r++){
    float s=0.f, sq=0.f;
    #pragma unroll
    for(int cT=0;cT<16;cT++){
      float v = acc[cT][r] + bias1[cT*16 + (lane&15)];
      s += v; sq += v*v;
    }
    #pragma unroll
    for(int m=1;m<16;m<<=1){ s += __shfl_xor(s,m,64); sq += __shfl_xor(sq,m,64); }
    float mu = s*(1.f/256.f);
    float var = sq*(1.f/256.f) - mu*mu;
    float rs = rsqrtf(var + LN_EPS);
    int rl = wid*16 + kgrp*4 + r;
    #pragma unroll
    for(int cT=0;cT<16;cT++){
      int col = cT*16 + (lane&15);
      float v = acc[cT][r] + bias1[col];
      float t = (v-mu)*rs*gam_f[col] + bet_f[col];
      t = fmaxf(t, 0.f);
      *(u16*)(T8 + rl*512 + ((col*2) ^ ((rl&7)<<4))) = f2bf(t);
    }
  }
  __syncthreads();

  // ---- t @ Wf2 (256 -> 128), out = x1 + ... + bf2 ----
  #pragma unroll
  for(int kT=0;kT<8;kT++)
    af[kT] = *(const short8v*)(T8 + arow*512 + (((kT*64) + kgrp*16) ^ ((arow&7)<<4)));
  f32x4 acc2[8];
  #pragma unroll
  for(int cT=0;cT<8;cT++){
    f32x4 a = {0.f,0.f,0.f,0.f};
    #pragma unroll
    for(int kT=0;kT<8;kT++){
      const short8v b8 = *(const short8v*)(pW2 + ((size_t)((kT*8+cT)*64 + lane)*8));
      a = __builtin_amdgcn_mfma_f32_16x16x32_bf16(af[kT], b8, a, 0,0,0);
    }
    acc2[cT] = a;
  }
  #pragma unroll
  for(int cT=0;cT<8;cT++){
    int col = cT*16 + (lane&15);
    float bv = bias2[col];
    #pragma unroll
    for(int r=0;r<4;r++){
      int rl = wid*16 + kgrp*4 + r;
      size_t gi = (size_t)(row0+rl)*CDIM + col;
      xio[gi] = xio[gi] + acc2[cT][r] + bv;
    }
  }
}

// ---------------- host ----------------
extern "C" void kernel_launch(void* const* d_in, const int* in_sizes, int n_in,
                              void* d_out, int out_size, void* d_ws, size_t ws_size,
                              hipStream_t stream){
  const float* feat    = (const float*)d_in[0];
  const int*   batch   = (const int*)d_in[1];
  const int*   lengths = (const int*)d_in[2];
  const float* scores  = (const float*)d_in[3];
  const float* Wq = (const float*)d_in[4];   const float* bq = (const float*)d_in[5];
  const float* Wk = (const float*)d_in[6];   const float* bk = (const float*)d_in[7];
  const float* Wv = (const float*)d_in[8];   const float* bv = (const float*)d_in[9];
  const float* Wg = (const float*)d_in[10];  const float* bg = (const float*)d_in[11];
  const float* Wp = (const float*)d_in[12];  const float* bp = (const float*)d_in[13];
  const float* g1 = (const float*)d_in[14];  const float* b1 = (const float*)d_in[15];
  const float* g2 = (const float*)d_in[16];  const float* b2 = (const float*)d_in[17];
  const float* Wf1 = (const float*)d_in[18]; const float* bf1 = (const float*)d_in[19];
  const float* gf  = (const float*)d_in[20]; const float* bfb = (const float*)d_in[21];
  const float* Wf2 = (const float*)d_in[22]; const float* bf2b = (const float*)d_in[23];

  char* ws = (char*)d_ws;
  size_t off = 0;
  auto alloc = [&](size_t bytes)->void*{
    void* p = ws + off;
    off = (off + bytes + 255) & ~(size_t)255;
    return p;
  };
  int*  gb     = (int*)alloc((size_t)N_PTS*4);
  int*  hist   = (int*)alloc((size_t)MAXB*4);
  int*  start  = (int*)alloc((size_t)MAXB*4);
  int*  cursor = (int*)alloc((size_t)MAXB*4);
  int*  sidx   = (int*)alloc((size_t)N_PTS*4);
  float* cent  = (float*)alloc((size_t)MAXB*CDIM*4);
  float* kc    = (float*)alloc((size_t)MAXB*CDIM*4);
  float* vc    = (float*)alloc((size_t)MAXB*CDIM*4);
  u16* pWq = (u16*)alloc((size_t)CDIM*CDIM*2);
  u16* pWg = (u16*)alloc((size_t)CDIM*CDIM*2);
  u16* pWp = (u16*)alloc((size_t)CDIM*CDIM*2);
  u16* pW1 = (u16*)alloc((size_t)CDIM*HID*2);
  u16* pW2 = (u16*)alloc((size_t)HID*CDIM*2);

  hipMemsetAsync(hist, 0, (size_t)MAXB*4, stream);

  k_bucket<<<N_PTS/256, 256, 0, stream>>>(batch, lengths, scores, gb, hist);
  k_scan<<<1, 256, 0, stream>>>(hist, start, cursor);
  k_scatter<<<N_PTS/256, 256, 0, stream>>>(gb, cursor, sidx);
  k_centroid<<<MAXB, 256, 0, stream>>>(feat, sidx, start, hist, g1, b1, cent);
  k_cgemm<<<MAXB, 128, 0, stream>>>(cent, Wk, bk, Wv, bv, kc, vc);

  k_pack<<<(CDIM*CDIM+255)/256, 256, 0, stream>>>(Wq, pWq, CDIM, CDIM);
  k_pack<<<(CDIM*CDIM+255)/256, 256, 0, stream>>>(Wg, pWg, CDIM, CDIM);
  k_pack<<<(CDIM*CDIM+255)/256, 256, 0, stream>>>(Wp, pWp, CDIM, CDIM);
  k_pack<<<(CDIM*HID+255)/256, 256, 0, stream>>>(Wf1, pW1, CDIM, HID);
  k_pack<<<(HID*CDIM+255)/256, 256, 0, stream>>>(Wf2, pW2, HID, CDIM);

  k_attn<<<N_PTS/64, 256, 0, stream>>>(feat, gb, kc, vc, pWq, pWg, pWp,
                                       bq, bg, bp, g1, b1, (float*)d_out);
  k_ffn<<<N_PTS/64, 256, 0, stream>>>((float*)d_out, pW1, pW2, bf1, gf, bfb, bf2b, g2, b2);
}